// Round 2
// baseline (590.076 us; speedup 1.0000x reference)
//
#include <hip/hip_runtime.h>
#include <hip/hip_bf16.h>

// Problem constants (from reference)
#define NNODES  50000
#define D       128
#define E       32
#define NMP     3
#define DEG     32
#define NEDGE   200000
#define B       1024
#define NC      8
#define S       16
#define NLAY    2

// ---------------- level-1 sampling: cur1/eid1 [B*S] ----------------
__global__ __launch_bounds__(256) void sample1_k(
    const int* __restrict__ ids,
    const int* __restrict__ adjn_mp, const int* __restrict__ adje_mp,
    int* __restrict__ cur1, int* __restrict__ eid1)
{
    int i = blockIdx.x * 256 + threadIdx.x;     // < B*S = 16384
    int b = i >> 4, j = i & 15;
    int node = ids[b];
    cur1[i] = adjn_mp[(size_t)node * DEG + j];
    eid1[i] = adje_mp[(size_t)node * DEG + j];
}

// ------------- agg over explicit neighbor lists (level-1 -> nin0 [B,160]) -------------
__global__ __launch_bounds__(64) void agg_lists_k(
    const float* __restrict__ feats, const float* __restrict__ ee_mp,
    const int* __restrict__ nbr, const int* __restrict__ eidx,
    float* __restrict__ nin)
{
    const int i = blockIdx.x;          // row
    const int t = threadIdx.x;         // 64
    float a0 = 0.f, a1 = 0.f, ae = 0.f;
    const int base = i * S;
    for (int j = 0; j < S; ++j) {
        int nb = nbr[base + j];
        a0 += feats[(size_t)nb * D + t];
        a1 += feats[(size_t)nb * D + 64 + t];
        if (t < E) {
            int ed = eidx[base + j];
            ae += ee_mp[(size_t)ed * E + t];
        }
    }
    const float inv = 1.0f / (float)S;
    nin[(size_t)i * 160 + t]      = a0 * inv;
    nin[(size_t)i * 160 + 64 + t] = a1 * inv;
    if (t < E) nin[(size_t)i * 160 + 128 + t] = ae * inv;
}

// ------------- agg reading adjacency directly (level-2 -> nin1 [B*S,160]) -------------
__global__ __launch_bounds__(64) void agg_adj_k(
    const float* __restrict__ feats, const float* __restrict__ ee_mp,
    const int* __restrict__ cur1,
    const int* __restrict__ adjn_mp, const int* __restrict__ adje_mp,
    float* __restrict__ nin)
{
    const int i = blockIdx.x;          // row < 16384
    const int t = threadIdx.x;         // 64
    const int node = cur1[i];
    float a0 = 0.f, a1 = 0.f, ae = 0.f;
    for (int j = 0; j < S; ++j) {
        int nb = adjn_mp[(size_t)node * DEG + j];
        a0 += feats[(size_t)nb * D + t];
        a1 += feats[(size_t)nb * D + 64 + t];
        if (t < E) {
            int ed = adje_mp[(size_t)node * DEG + j];
            ae += ee_mp[(size_t)ed * E + t];
        }
    }
    const float inv = 1.0f / (float)S;
    nin[(size_t)i * 160 + t]      = a0 * inv;
    nin[(size_t)i * 160 + 64 + t] = a1 * inv;
    if (t < E) nin[(size_t)i * 160 + 128 + t] = ae * inv;
}

// ------------- feature update: out = relu(A @ Wself + nin @ Wneigh)  [nrows,128] -------------
// A rows: either gather feats[gidx[i]] (gidx != nullptr) or dense directA[i].
#define FR 8
__global__ __launch_bounds__(128) void feat_update_k(
    const float* __restrict__ feats, const int* __restrict__ gidx,
    const float* __restrict__ directA,
    const float* __restrict__ nin,
    const float* __restrict__ Wself, const float* __restrict__ Wneigh,
    float* __restrict__ out, int nrows)
{
    __shared__ float A[FR][D];
    __shared__ float Nn[FR][160];
    const int t = threadIdx.x;         // 128 -> output dim
    const int row0 = blockIdx.x * FR;
    for (int r = 0; r < FR; ++r) {
        int i = row0 + r;
        int ii = i < nrows ? i : (nrows - 1);
        if (gidx) A[r][t] = feats[(size_t)gidx[ii] * D + t];
        else      A[r][t] = directA[(size_t)ii * D + t];
        Nn[r][t] = nin[(size_t)ii * 160 + t];
        if (t < 32) Nn[r][128 + t] = nin[(size_t)ii * 160 + 128 + t];
    }
    __syncthreads();
    float acc[FR];
#pragma unroll
    for (int r = 0; r < FR; ++r) acc[r] = 0.f;
    // self part: K = 128
    for (int k = 0; k < D; k += 4) {
        float w0 = Wself[(k + 0) * D + t];
        float w1 = Wself[(k + 1) * D + t];
        float w2 = Wself[(k + 2) * D + t];
        float w3 = Wself[(k + 3) * D + t];
#pragma unroll
        for (int r = 0; r < FR; ++r) {
            float4 a = *(const float4*)&A[r][k];
            acc[r] = fmaf(a.x, w0, fmaf(a.y, w1, fmaf(a.z, w2, fmaf(a.w, w3, acc[r]))));
        }
    }
    // neigh part: K = 160
    for (int k = 0; k < 160; k += 4) {
        float w0 = Wneigh[(k + 0) * D + t];
        float w1 = Wneigh[(k + 1) * D + t];
        float w2 = Wneigh[(k + 2) * D + t];
        float w3 = Wneigh[(k + 3) * D + t];
#pragma unroll
        for (int r = 0; r < FR; ++r) {
            float4 a = *(const float4*)&Nn[r][k];
            acc[r] = fmaf(a.x, w0, fmaf(a.y, w1, fmaf(a.z, w2, fmaf(a.w, w3, acc[r]))));
        }
    }
    for (int r = 0; r < FR; ++r) {
        int i = row0 + r;
        if (i < nrows) out[(size_t)i * D + t] = fmaxf(acc[r], 0.f);
    }
}

// ------------- edge update: e0p = relu(concat(rep(f0p,S), f1p, E1) @ We) [B*S,32] -------------
__global__ __launch_bounds__(256) void edge_update_k(
    const float* __restrict__ f0p, const float* __restrict__ f1p,
    const float* __restrict__ ee_mp, const int* __restrict__ eid1,
    const float* __restrict__ We, float* __restrict__ e0p)
{
    __shared__ float X[8][288];
    const int t = threadIdx.x;          // 256
    const int row0 = blockIdx.x * 8;
    for (int e = t; e < 8 * 288; e += 256) {
        int r = e / 288, k = e % 288;
        int i = row0 + r;
        float v;
        if (k < 128)      v = f0p[(size_t)(i >> 4) * D + k];
        else if (k < 256) v = f1p[(size_t)i * D + (k - 128)];
        else              v = ee_mp[(size_t)eid1[i] * E + (k - 256)];
        X[r][k] = v;
    }
    __syncthreads();
    const int c = t & 31;
    const int r = t >> 5;               // 8 rows
    float acc = 0.f;
    for (int k = 0; k < 288; k += 4) {
        float4 x = *(const float4*)&X[r][k];
        float w0 = We[(k + 0) * E + c];
        float w1 = We[(k + 1) * E + c];
        float w2 = We[(k + 2) * E + c];
        float w3 = We[(k + 3) * E + c];
        acc = fmaf(x.x, w0, fmaf(x.y, w1, fmaf(x.z, w2, fmaf(x.w, w3, acc))));
    }
    e0p[(size_t)(row0 + r) * E + c] = fmaxf(acc, 0.f);
}

// ------------- layer-1 aggregation (sequential segments) -> agg1 [B,160] -------------
__global__ __launch_bounds__(64) void agg_seq_k(
    const float* __restrict__ f1p, const float* __restrict__ e0p,
    float* __restrict__ agg1)
{
    const int b = blockIdx.x;
    const int t = threadIdx.x;
    float a0 = 0.f, a1 = 0.f, ae = 0.f;
    for (int j = 0; j < S; ++j) {
        size_t r = (size_t)b * S + j;
        a0 += f1p[r * D + t];
        a1 += f1p[r * D + 64 + t];
        if (t < E) ae += e0p[r * E + t];
    }
    const float inv = 1.0f / (float)S;
    agg1[(size_t)b * 160 + t]      = a0 * inv;
    agg1[(size_t)b * 160 + 64 + t] = a1 * inv;
    if (t < E) agg1[(size_t)b * 160 + 128 + t] = ae * inv;
}

// ------------- metapath attention + normalize + fc -------------
__global__ __launch_bounds__(64) void finalize_k(
    const float* __restrict__ outs,     // [NMP][B][D]
    const float* __restrict__ attn, const float* __restrict__ fcw,
    const float* __restrict__ fcb,
    float* __restrict__ out)            // [B][NC]
{
    const int b = blockIdx.x;
    const int t = threadIdx.x;          // 64; handles dims t and t+64
    float v0[NMP], v1[NMP], sc[NMP];
    float at0 = attn[t], at1 = attn[64 + t];
#pragma unroll
    for (int mp = 0; mp < NMP; ++mp) {
        v0[mp] = outs[((size_t)mp * B + b) * D + t];
        v1[mp] = outs[((size_t)mp * B + b) * D + 64 + t];
        float p = v0[mp] * at0 + v1[mp] * at1;
#pragma unroll
        for (int off = 32; off; off >>= 1) p += __shfl_xor(p, off);
        sc[mp] = tanhf(p);
    }
    float mx = fmaxf(sc[0], fmaxf(sc[1], sc[2]));
    float e0 = expf(sc[0] - mx), e1 = expf(sc[1] - mx), e2 = expf(sc[2] - mx);
    float isum = 1.f / (e0 + e1 + e2);
    float b0 = e0 * isum, b1 = e1 * isum, b2 = e2 * isum;
    float emb0 = b0 * v0[0] + b1 * v0[1] + b2 * v0[2];
    float emb1 = b0 * v1[0] + b1 * v1[1] + b2 * v1[2];
    float nn = emb0 * emb0 + emb1 * emb1;
#pragma unroll
    for (int off = 32; off; off >>= 1) nn += __shfl_xor(nn, off);
    float innorm = 1.f / fmaxf(sqrtf(nn), 1e-12f);
    emb0 *= innorm; emb1 *= innorm;
    float pc[NC];
#pragma unroll
    for (int c = 0; c < NC; ++c) {
        float p = emb0 * fcw[t * NC + c] + emb1 * fcw[(64 + t) * NC + c];
#pragma unroll
        for (int off = 32; off; off >>= 1) p += __shfl_xor(p, off);
        pc[c] = p;
    }
    if (t == 0) {
#pragma unroll
        for (int c = 0; c < NC; ++c)
            out[(size_t)b * NC + c] = pc[c] + fcb[c];
    }
}

extern "C" void kernel_launch(void* const* d_in, const int* in_sizes, int n_in,
                              void* d_out, int out_size, void* d_ws, size_t ws_size,
                              hipStream_t stream) {
    const int* ids    = (const int*)d_in[0];
    const float* feats    = (const float*)d_in[1];
    const float* edge_emb = (const float*)d_in[2];
    const int* adjn   = (const int*)d_in[3];
    const int* adje   = (const int*)d_in[4];
    const float* Wself    = (const float*)d_in[5];
    const float* Wneigh   = (const float*)d_in[6];
    const float* Wedge    = (const float*)d_in[7];
    const float* attn     = (const float*)d_in[8];
    const float* fcw      = (const float*)d_in[9];
    const float* fcb      = (const float*)d_in[10];
    float* out = (float*)d_out;

    // workspace layout (all fully written before read each call); total ~24.5 MB
    int* cur1   = (int*)d_ws;                       // 16384
    int* eid1   = cur1 + B * S;                     // 16384
    float* nin1 = (float*)(eid1 + B * S);           // 16384*160
    float* nin0 = nin1 + (size_t)B * S * 160;       // 1024*160
    float* f0p  = nin0 + (size_t)B * 160;           // 1024*128
    float* f1p  = f0p + (size_t)B * D;              // 16384*128
    float* e0p  = f1p + (size_t)B * S * D;          // 16384*32
    float* agg1 = e0p + (size_t)B * S * E;          // 1024*160
    float* outs = agg1 + (size_t)B * 160;           // 3*1024*128

    for (int mp = 0; mp < NMP; ++mp) {
        const int* adjn_mp = adjn + (size_t)mp * NNODES * DEG;
        const int* adje_mp = adje + (size_t)mp * NNODES * DEG;
        const float* ee_mp = edge_emb + (size_t)mp * NEDGE * E;
        const float* Ws0 = Wself  + ((size_t)mp * NLAY + 0) * D * D;
        const float* Ws1 = Wself  + ((size_t)mp * NLAY + 1) * D * D;
        const float* Wn0 = Wneigh + ((size_t)mp * NLAY + 0) * 160 * D;
        const float* Wn1 = Wneigh + ((size_t)mp * NLAY + 1) * 160 * D;
        const float* We0 = Wedge  + ((size_t)mp * NLAY + 0) * 288 * E;

        sample1_k<<<B * S / 256, 256, 0, stream>>>(ids, adjn_mp, adje_mp, cur1, eid1);
        agg_lists_k<<<B, 64, 0, stream>>>(feats, ee_mp, cur1, eid1, nin0);
        agg_adj_k<<<B * S, 64, 0, stream>>>(feats, ee_mp, cur1, adjn_mp, adje_mp, nin1);
        feat_update_k<<<B / FR, 128, 0, stream>>>(feats, ids, nullptr, nin0, Ws0, Wn0, f0p, B);
        feat_update_k<<<B * S / FR, 128, 0, stream>>>(feats, cur1, nullptr, nin1, Ws0, Wn0, f1p, B * S);
        edge_update_k<<<B * S / 8, 256, 0, stream>>>(f0p, f1p, ee_mp, eid1, We0, e0p);
        agg_seq_k<<<B, 64, 0, stream>>>(f1p, e0p, agg1);
        feat_update_k<<<B / FR, 128, 0, stream>>>(feats, nullptr, f0p, agg1, Ws1, Wn1,
                                                  outs + (size_t)mp * B * D, B);
    }
    finalize_k<<<B, 64, 0, stream>>>(outs, attn, fcw, fcb, out);
}

// Round 3
// 340.983 us; speedup vs baseline: 1.7305x; 1.7305x over previous
//
#include <hip/hip_runtime.h>

// Problem constants
#define NNODES  50000
#define D       128
#define E       32
#define NMP     3
#define DEG     32
#define NEDGE   200000
#define B       1024
#define NC      8
#define S       16

#define RPM      17408   // rows per mp in L0 row space (16384 level-1 + 1024 level-0)
#define NKT      9       // K tiles of 32 (K=288)
#define WSTRIDE  36864   // ushorts per (mp,lay) feat-weight block: 9*4*128*8
#define WESTRIDE 9216    // ushorts per mp edge-weight block: 9*4*32*8

typedef float f4 __attribute__((ext_vector_type(4)));
typedef short bh8 __attribute__((ext_vector_type(8)));   // 8 bf16 in 4 VGPRs

static __device__ __forceinline__ unsigned short f2bf(float f) {
    unsigned int u = __float_as_uint(f);
    u = u + 0x7FFFu + ((u >> 16) & 1u);   // RN-even
    return (unsigned short)(u >> 16);
}
static __device__ __forceinline__ float bf2f(unsigned short h) {
    return __uint_as_float(((unsigned int)h) << 16);
}

// ---------- one-shot conversions: feats->bf16 table, weights->swizzled bf16 frags ----------
// B-fragment order: dst[((kt*4+q)*N + n)*8 + j] = W[k = kt*32+q*8+j][n]
__global__ __launch_bounds__(256) void convert_k(
    const float* __restrict__ feats, const float* __restrict__ Ws,
    const float* __restrict__ Wn, const float* __restrict__ We,
    unsigned short* __restrict__ fb, unsigned short* __restrict__ WT0,
    unsigned short* __restrict__ WTe)
{
    int i = blockIdx.x * 256 + threadIdx.x;
    if (i < 1600000) {                          // feats: 50000*128/4 float4 tasks
        float4 v = ((const float4*)feats)[i];
        unsigned int p0 = (unsigned int)f2bf(v.x) | ((unsigned int)f2bf(v.y) << 16);
        unsigned int p1 = (unsigned int)f2bf(v.z) | ((unsigned int)f2bf(v.w) << 16);
        ((uint2*)fb)[i] = make_uint2(p0, p1);
    } else if (i < 1600000 + 6 * WSTRIDE) {     // feat weights: [mp][lay] K=288 (Ws||Wn), N=128
        int i2 = i - 1600000;
        int ml = i2 / WSTRIDE, e = i2 % WSTRIDE;
        int j = e & 7, t1 = e >> 3;
        int n = t1 & 127, t2 = t1 >> 7;
        int q = t2 & 3, kt = t2 >> 2;
        int k = kt * 32 + q * 8 + j;
        float v = (k < 128) ? Ws[((size_t)ml * 128 + k) * 128 + n]
                            : Wn[((size_t)ml * 160 + (k - 128)) * 128 + n];
        WT0[(size_t)ml * WSTRIDE + e] = f2bf(v);
    } else if (i < 1600000 + 6 * WSTRIDE + 3 * WESTRIDE) {  // edge weights: [mp][lay0] K=288,N=32
        int i3 = i - 1600000 - 6 * WSTRIDE;
        int mp = i3 / WESTRIDE, e = i3 % WESTRIDE;
        int j = e & 7, t1 = e >> 3;
        int n = t1 & 31, t2 = t1 >> 5;
        int q = t2 & 3, kt = t2 >> 2;
        int k = kt * 32 + q * 8 + j;
        float v = We[(((size_t)mp * 2) * 288 + k) * 32 + n];
        WTe[(size_t)mp * WESTRIDE + e] = f2bf(v);
    }
}

// ---------- level-1 sampling; gx row space: [0,16384)=cur1, [16384,17408)=ids ----------
__global__ __launch_bounds__(256) void sample_k(
    const int* __restrict__ ids, const int* __restrict__ adjn,
    const int* __restrict__ adje, int* __restrict__ gx, int* __restrict__ eid1)
{
    int mp = blockIdx.y;
    int i = blockIdx.x * 256 + threadIdx.x;
    const int* an = adjn + (size_t)mp * NNODES * DEG;
    const int* ae = adje + (size_t)mp * NNODES * DEG;
    if (i < 16384) {
        int node = ids[i >> 4];
        gx[mp * RPM + i]     = an[(size_t)node * DEG + (i & 15)];
        eid1[mp * 16384 + i] = ae[(size_t)node * DEG + (i & 15)];
    } else if (i < RPM) {
        gx[mp * RPM + i] = ids[i - 16384];
    }
}

// ---------- gather-mean -> nin [mp][RPM][160] bf16 (rows<16384: via adjacency; else: via lists) ----------
__global__ __launch_bounds__(256) void aggnin_k(
    const unsigned short* __restrict__ fb, const float* __restrict__ edge_emb,
    const int* __restrict__ adjn, const int* __restrict__ adje,
    const int* __restrict__ gx, const int* __restrict__ eid1,
    unsigned short* __restrict__ nin)
{
    int mp = blockIdx.y;
    int r = blockIdx.x * 4 + (threadIdx.x >> 6);   // < 17408
    int t = threadIdx.x & 63;
    const float* ee = edge_emb + (size_t)mp * NEDGE * E;
    float s0 = 0.f, s1 = 0.f, se = 0.f;
    if (r < 16384) {
        int node = gx[mp * RPM + r];
        const int* an = adjn + ((size_t)mp * NNODES + node) * DEG;
        const int* ap = adje + ((size_t)mp * NNODES + node) * DEG;
#pragma unroll 4
        for (int j = 0; j < S; ++j) {
            int nb = an[j];
            unsigned int u = ((const unsigned int*)fb)[(size_t)nb * 64 + t];
            s0 += bf2f((unsigned short)(u & 0xFFFF));
            s1 += bf2f((unsigned short)(u >> 16));
            if (t < E) se += ee[(size_t)ap[j] * E + t];
        }
    } else {
        int b = r - 16384;
        const int* nbl = gx + mp * RPM + b * S;
        const int* edl = eid1 + mp * 16384 + b * S;
#pragma unroll 4
        for (int j = 0; j < S; ++j) {
            int nb = nbl[j];
            unsigned int u = ((const unsigned int*)fb)[(size_t)nb * 64 + t];
            s0 += bf2f((unsigned short)(u & 0xFFFF));
            s1 += bf2f((unsigned short)(u >> 16));
            if (t < E) se += ee[(size_t)edl[j] * E + t];
        }
    }
    const float inv = 1.0f / (float)S;
    unsigned short* row = nin + ((size_t)mp * RPM + r) * 160;
    ((unsigned int*)row)[t] =
        (unsigned int)f2bf(s0 * inv) | ((unsigned int)f2bf(s1 * inv) << 16);
    if (t < E) row[128 + t] = f2bf(se * inv);
}

// ---------- MFMA feat GEMM: out = relu(A @ [Wself;Wneigh]), K=288, N=128 ----------
// mode 0 (layer 0): A rows gathered from fb via gx; nin stride RPM; out bf16 fout, rows/mp=17408
// mode 1 (layer 1): A rows direct from fout's f0 region; nin=agg1 stride B; out f32, rows/mp=1024
__global__ __launch_bounds__(256) void gemm_feat_k(
    const unsigned short* __restrict__ fb, const int* __restrict__ gx,
    const unsigned short* __restrict__ fout_in,
    const unsigned short* __restrict__ nin,
    const unsigned short* __restrict__ WT0,
    unsigned short* __restrict__ outb, float* __restrict__ outf, int mode)
{
    const int mp = blockIdx.y;
    const int w = threadIdx.x >> 6;
    const int l = threadIdx.x & 63;
    const int q = l >> 4, lm = l & 15;
    const int m0 = blockIdx.x * 128 + w * 32;          // wave: 2 m-tiles (32 rows)
    const int ninStride = mode ? B : RPM;
    const unsigned short* wb = WT0 + ((size_t)mp * 2 + mode) * WSTRIDE;

    const unsigned short* ap[2];
    const unsigned short* np[2];
#pragma unroll
    for (int mt = 0; mt < 2; ++mt) {
        int row = m0 + mt * 16 + lm;
        if (mode == 0) {
            int node = gx[mp * RPM + row];
            ap[mt] = fb + (size_t)node * 128;
        } else {
            ap[mt] = fout_in + ((size_t)mp * RPM + 16384 + row) * 128;
        }
        np[mt] = nin + ((size_t)mp * ninStride + row) * 160;
    }

    f4 acc[2][8];
#pragma unroll
    for (int mt = 0; mt < 2; ++mt)
#pragma unroll
        for (int nt = 0; nt < 8; ++nt) acc[mt][nt] = (f4){0.f, 0.f, 0.f, 0.f};

#pragma unroll
    for (int kt = 0; kt < NKT; ++kt) {
        const int k0 = kt * 32 + q * 8;
        bh8 a[2];
#pragma unroll
        for (int mt = 0; mt < 2; ++mt) {
            const unsigned short* p = (k0 < 128) ? (ap[mt] + k0) : (np[mt] + (k0 - 128));
            a[mt] = *(const bh8*)p;
        }
        const unsigned short* wrow = wb + ((size_t)(kt * 4 + q) * 128 + lm) * 8;
#pragma unroll
        for (int nt = 0; nt < 8; ++nt) {
            bh8 bf = *(const bh8*)(wrow + nt * 16 * 8);
#pragma unroll
            for (int mt = 0; mt < 2; ++mt)
                acc[mt][nt] = __builtin_amdgcn_mfma_f32_16x16x32_bf16(a[mt], bf, acc[mt][nt], 0, 0, 0);
        }
    }

    if (mode == 0) {
#pragma unroll
        for (int mt = 0; mt < 2; ++mt)
#pragma unroll
            for (int nt = 0; nt < 8; ++nt)
#pragma unroll
                for (int rr = 0; rr < 4; ++rr) {
                    int row = m0 + mt * 16 + q * 4 + rr;   // C/D: col=lane&15, row=quad*4+reg
                    int col = nt * 16 + lm;
                    outb[((size_t)mp * RPM + row) * 128 + col] = f2bf(fmaxf(acc[mt][nt][rr], 0.f));
                }
    } else {
#pragma unroll
        for (int mt = 0; mt < 2; ++mt)
#pragma unroll
            for (int nt = 0; nt < 8; ++nt)
#pragma unroll
                for (int rr = 0; rr < 4; ++rr) {
                    int row = m0 + mt * 16 + q * 4 + rr;
                    int col = nt * 16 + lm;
                    outf[((size_t)mp * B + row) * 128 + col] = fmaxf(acc[mt][nt][rr], 0.f);
                }
    }
}

// ---------- MFMA edge GEMM: e0p = relu(concat(rep(f0,S), f1, E0) @ We), K=288, N=32 ----------
__global__ __launch_bounds__(256) void gemm_edge_k(
    const unsigned short* __restrict__ fout, const float* __restrict__ edge_emb,
    const int* __restrict__ eid1, const unsigned short* __restrict__ WTe,
    unsigned short* __restrict__ e0p)
{
    const int mp = blockIdx.y;
    const int w = threadIdx.x >> 6, l = threadIdx.x & 63;
    const int q = l >> 4, lm = l & 15;
    const int m0 = blockIdx.x * 256 + w * 64;          // wave: 4 m-tiles (64 rows)
    const unsigned short* we = WTe + (size_t)mp * WESTRIDE;
    const unsigned short* f1base = fout + (size_t)mp * RPM * 128;
    const unsigned short* f0base = fout + ((size_t)mp * RPM + 16384) * 128;
    const float* ee = edge_emb + (size_t)mp * NEDGE * E;

    const unsigned short* a1p[4];
    const unsigned short* a0p[4];
    int eidL[4];
#pragma unroll
    for (int mt = 0; mt < 4; ++mt) {
        int row = m0 + mt * 16 + lm;
        a1p[mt] = f1base + (size_t)row * 128;
        a0p[mt] = f0base + (size_t)(row >> 4) * 128;
        eidL[mt] = eid1[mp * 16384 + row];
    }

    f4 acc[4][2];
#pragma unroll
    for (int mt = 0; mt < 4; ++mt) { acc[mt][0] = (f4){0,0,0,0}; acc[mt][1] = (f4){0,0,0,0}; }

#pragma unroll
    for (int kt = 0; kt < NKT; ++kt) {
        const int k0 = kt * 32 + q * 8;
        bh8 a[4];
#pragma unroll
        for (int mt = 0; mt < 4; ++mt) {
            if (kt < 4) {
                a[mt] = *(const bh8*)(a0p[mt] + k0);
            } else if (kt < 8) {
                a[mt] = *(const bh8*)(a1p[mt] + (k0 - 128));
            } else {
                const float* ep = ee + (size_t)eidL[mt] * E + q * 8;
                float4 v0 = *(const float4*)ep;
                float4 v1 = *(const float4*)(ep + 4);
                bh8 tv;
                tv[0] = (short)f2bf(v0.x); tv[1] = (short)f2bf(v0.y);
                tv[2] = (short)f2bf(v0.z); tv[3] = (short)f2bf(v0.w);
                tv[4] = (short)f2bf(v1.x); tv[5] = (short)f2bf(v1.y);
                tv[6] = (short)f2bf(v1.z); tv[7] = (short)f2bf(v1.w);
                a[mt] = tv;
            }
        }
        const unsigned short* wrow = we + ((size_t)(kt * 4 + q) * 32 + lm) * 8;
        bh8 b0 = *(const bh8*)(wrow);
        bh8 b1 = *(const bh8*)(wrow + 16 * 8);
#pragma unroll
        for (int mt = 0; mt < 4; ++mt) {
            acc[mt][0] = __builtin_amdgcn_mfma_f32_16x16x32_bf16(a[mt], b0, acc[mt][0], 0, 0, 0);
            acc[mt][1] = __builtin_amdgcn_mfma_f32_16x16x32_bf16(a[mt], b1, acc[mt][1], 0, 0, 0);
        }
    }
#pragma unroll
    for (int mt = 0; mt < 4; ++mt)
#pragma unroll
        for (int nt = 0; nt < 2; ++nt)
#pragma unroll
            for (int rr = 0; rr < 4; ++rr) {
                int row = m0 + mt * 16 + q * 4 + rr;
                int col = nt * 16 + lm;
                e0p[((size_t)mp * 16384 + row) * 32 + col] = f2bf(fmaxf(acc[mt][nt][rr], 0.f));
            }
}

// ---------- layer-1 aggregation (sequential segments) -> agg1 [mp][B][160] bf16 ----------
__global__ __launch_bounds__(256) void aggseq_k(
    const unsigned short* __restrict__ fout, const unsigned short* __restrict__ e0p,
    unsigned short* __restrict__ agg1)
{
    int mp = blockIdx.y;
    int bRow = blockIdx.x * 4 + (threadIdx.x >> 6);   // < 1024
    int t = threadIdx.x & 63;
    const unsigned short* f1 = fout + ((size_t)mp * RPM + (size_t)bRow * 16) * 128;
    const unsigned short* e0 = e0p + ((size_t)mp * 16384 + (size_t)bRow * 16) * 32;
    float s0 = 0.f, s1 = 0.f, se = 0.f;
#pragma unroll 4
    for (int j = 0; j < S; ++j) {
        unsigned int u = ((const unsigned int*)(f1 + j * 128))[t];
        s0 += bf2f((unsigned short)(u & 0xFFFF));
        s1 += bf2f((unsigned short)(u >> 16));
        if (t < E) se += bf2f(e0[j * 32 + t]);
    }
    const float inv = 1.0f / (float)S;
    unsigned short* row = agg1 + ((size_t)mp * B + bRow) * 160;
    ((unsigned int*)row)[t] =
        (unsigned int)f2bf(s0 * inv) | ((unsigned int)f2bf(s1 * inv) << 16);
    if (t < E) row[128 + t] = f2bf(se * inv);
}

// ---------- metapath attention + normalize + fc ----------
__global__ __launch_bounds__(64) void finalize_k(
    const float* __restrict__ outs,     // [NMP][B][D] f32
    const float* __restrict__ attn, const float* __restrict__ fcw,
    const float* __restrict__ fcb, float* __restrict__ out)
{
    const int b = blockIdx.x;
    const int t = threadIdx.x;
    float v0[NMP], v1[NMP], sc[NMP];
    float at0 = attn[t], at1 = attn[64 + t];
#pragma unroll
    for (int mp = 0; mp < NMP; ++mp) {
        v0[mp] = outs[((size_t)mp * B + b) * D + t];
        v1[mp] = outs[((size_t)mp * B + b) * D + 64 + t];
        float p = v0[mp] * at0 + v1[mp] * at1;
#pragma unroll
        for (int off = 32; off; off >>= 1) p += __shfl_xor(p, off);
        sc[mp] = tanhf(p);
    }
    float mx = fmaxf(sc[0], fmaxf(sc[1], sc[2]));
    float e0 = expf(sc[0] - mx), e1 = expf(sc[1] - mx), e2 = expf(sc[2] - mx);
    float isum = 1.f / (e0 + e1 + e2);
    float b0 = e0 * isum, b1 = e1 * isum, b2 = e2 * isum;
    float emb0 = b0 * v0[0] + b1 * v0[1] + b2 * v0[2];
    float emb1 = b0 * v1[0] + b1 * v1[1] + b2 * v1[2];
    float nn = emb0 * emb0 + emb1 * emb1;
#pragma unroll
    for (int off = 32; off; off >>= 1) nn += __shfl_xor(nn, off);
    float innorm = 1.f / fmaxf(sqrtf(nn), 1e-12f);
    emb0 *= innorm; emb1 *= innorm;
    float pc[NC];
#pragma unroll
    for (int c = 0; c < NC; ++c) {
        float p = emb0 * fcw[t * NC + c] + emb1 * fcw[(64 + t) * NC + c];
#pragma unroll
        for (int off = 32; off; off >>= 1) p += __shfl_xor(p, off);
        pc[c] = p;
    }
    if (t == 0) {
#pragma unroll
        for (int c = 0; c < NC; ++c)
            out[(size_t)b * NC + c] = pc[c] + fcb[c];
    }
}

extern "C" void kernel_launch(void* const* d_in, const int* in_sizes, int n_in,
                              void* d_out, int out_size, void* d_ws, size_t ws_size,
                              hipStream_t stream) {
    const int* ids        = (const int*)d_in[0];
    const float* feats    = (const float*)d_in[1];
    const float* edge_emb = (const float*)d_in[2];
    const int* adjn       = (const int*)d_in[3];
    const int* adje       = (const int*)d_in[4];
    const float* Ws       = (const float*)d_in[5];
    const float* Wn       = (const float*)d_in[6];
    const float* We       = (const float*)d_in[7];
    const float* attn     = (const float*)d_in[8];
    const float* fcw      = (const float*)d_in[9];
    const float* fcb      = (const float*)d_in[10];
    float* out = (float*)d_out;

    // workspace layout (~49.5 MB; all regions fully written before read each call)
    char* p = (char*)d_ws;
    unsigned short* WT0 = (unsigned short*)p; p += (size_t)6 * WSTRIDE * 2;
    unsigned short* WTe = (unsigned short*)p; p += (size_t)3 * WESTRIDE * 2;
    unsigned short* fb  = (unsigned short*)p; p += (size_t)NNODES * 128 * 2;
    int* gx   = (int*)p;                      p += (size_t)3 * RPM * 4;
    int* eid1 = (int*)p;                      p += (size_t)3 * 16384 * 4;
    unsigned short* nin  = (unsigned short*)p; p += (size_t)3 * RPM * 160 * 2;
    unsigned short* fout = (unsigned short*)p; p += (size_t)3 * RPM * 128 * 2;
    unsigned short* e0p  = (unsigned short*)p; p += (size_t)3 * 16384 * 32 * 2;
    unsigned short* agg1 = (unsigned short*)p; p += (size_t)3 * B * 160 * 2;
    float* outs = (float*)p;                   p += (size_t)3 * B * 128 * 4;

    convert_k<<<7222, 256, 0, stream>>>(feats, Ws, Wn, We, fb, WT0, WTe);
    sample_k<<<dim3(68, 3), 256, 0, stream>>>(ids, adjn, adje, gx, eid1);
    aggnin_k<<<dim3(RPM / 4, 3), 256, 0, stream>>>(fb, edge_emb, adjn, adje, gx, eid1, nin);
    gemm_feat_k<<<dim3(136, 3), 256, 0, stream>>>(fb, gx, fout, nin, WT0, fout, nullptr, 0);
    gemm_edge_k<<<dim3(64, 3), 256, 0, stream>>>(fout, edge_emb, eid1, WTe, e0p);
    aggseq_k<<<dim3(256, 3), 256, 0, stream>>>(fout, e0p, agg1);
    gemm_feat_k<<<dim3(8, 3), 256, 0, stream>>>(fb, nullptr, fout, agg1, WT0, nullptr, outs, 1);
    finalize_k<<<B, 64, 0, stream>>>(outs, attn, fcw, fcb, out);
}

// Round 4
// 255.407 us; speedup vs baseline: 2.3103x; 1.3351x over previous
//
#include <hip/hip_runtime.h>

// Problem constants
#define NNODES  50000
#define D       128
#define E       32
#define NMP     3
#define DEG     32
#define NEDGE   200000
#define B       1024
#define NC      8
#define S       16

#define RPM      17408   // rows per mp in L0 row space (16384 level-1 + 1024 level-0)
#define NKT      9       // K tiles of 32 (K=288)
#define WSTRIDE  36864   // ushorts per (mp,lay) feat-weight block: 9*4*128*8
#define WESTRIDE 9216    // ushorts per mp edge-weight block: 9*4*32*8

typedef float f4 __attribute__((ext_vector_type(4)));
typedef short bh8 __attribute__((ext_vector_type(8)));   // 8 bf16 in 4 VGPRs

static __device__ __forceinline__ unsigned short f2bf(float f) {
    unsigned int u = __float_as_uint(f);
    u = u + 0x7FFFu + ((u >> 16) & 1u);   // RN-even
    return (unsigned short)(u >> 16);
}
static __device__ __forceinline__ float bf2f(unsigned short h) {
    return __uint_as_float(((unsigned int)h) << 16);
}

// ---------- one-shot conversions: feats->bf16 table, weights->swizzled bf16 frags ----------
// B-fragment order: dst[((kt*4+q)*N + n)*8 + j] = W[k = kt*32+q*8+j][n]
__global__ __launch_bounds__(256) void convert_k(
    const float* __restrict__ feats, const float* __restrict__ Ws,
    const float* __restrict__ Wn, const float* __restrict__ We,
    unsigned short* __restrict__ fb, unsigned short* __restrict__ WT0,
    unsigned short* __restrict__ WTe)
{
    int i = blockIdx.x * 256 + threadIdx.x;
    if (i < 1600000) {                          // feats: 50000*128/4 float4 tasks
        float4 v = ((const float4*)feats)[i];
        unsigned int p0 = (unsigned int)f2bf(v.x) | ((unsigned int)f2bf(v.y) << 16);
        unsigned int p1 = (unsigned int)f2bf(v.z) | ((unsigned int)f2bf(v.w) << 16);
        ((uint2*)fb)[i] = make_uint2(p0, p1);
    } else if (i < 1600000 + 6 * WSTRIDE) {     // feat weights: [mp][lay] K=288 (Ws||Wn), N=128
        int i2 = i - 1600000;
        int ml = i2 / WSTRIDE, e = i2 % WSTRIDE;
        int j = e & 7, t1 = e >> 3;
        int n = t1 & 127, t2 = t1 >> 7;
        int q = t2 & 3, kt = t2 >> 2;
        int k = kt * 32 + q * 8 + j;
        float v = (k < 128) ? Ws[((size_t)ml * 128 + k) * 128 + n]
                            : Wn[((size_t)ml * 160 + (k - 128)) * 128 + n];
        WT0[(size_t)ml * WSTRIDE + e] = f2bf(v);
    } else if (i < 1600000 + 6 * WSTRIDE + 3 * WESTRIDE) {  // edge weights: [mp][lay0] K=288,N=32
        int i3 = i - 1600000 - 6 * WSTRIDE;
        int mp = i3 / WESTRIDE, e = i3 % WESTRIDE;
        int j = e & 7, t1 = e >> 3;
        int n = t1 & 31, t2 = t1 >> 5;
        int q = t2 & 3, kt = t2 >> 2;
        int k = kt * 32 + q * 8 + j;
        float v = We[(((size_t)mp * 2) * 288 + k) * 32 + n];
        WTe[(size_t)mp * WESTRIDE + e] = f2bf(v);
    }
}

// ---------- level-1 sampling; gx row space: [0,16384)=cur1, [16384,17408)=ids ----------
__global__ __launch_bounds__(256) void sample_k(
    const int* __restrict__ ids, const int* __restrict__ adjn,
    const int* __restrict__ adje, int* __restrict__ gx, int* __restrict__ eid1)
{
    int mp = blockIdx.y;
    int i = blockIdx.x * 256 + threadIdx.x;
    const int* an = adjn + (size_t)mp * NNODES * DEG;
    const int* ae = adje + (size_t)mp * NNODES * DEG;
    if (i < 16384) {
        int node = ids[i >> 4];
        gx[mp * RPM + i]     = an[(size_t)node * DEG + (i & 15)];
        eid1[mp * 16384 + i] = ae[(size_t)node * DEG + (i & 15)];
    } else if (i < RPM) {
        gx[mp * RPM + i] = ids[i - 16384];
    }
}

// ---------- gather-mean -> nin [mp][RPM][160] bf16 ----------
// One wave per row. Index lists via scalar loads; all gathers issued before use
// (full unroll -> ~24 outstanding loads/wave). Edge loads paired across wave halves.
__global__ __launch_bounds__(256) void aggnin_k(
    const unsigned short* __restrict__ fb, const float* __restrict__ edge_emb,
    const int* __restrict__ adjn, const int* __restrict__ adje,
    const int* __restrict__ gx, const int* __restrict__ eid1,
    unsigned short* __restrict__ nin)
{
    const int mp = blockIdx.y;
    const int r = blockIdx.x * 4 + (threadIdx.x >> 6);   // < 17408, wave-uniform
    const int t = threadIdx.x & 63;
    const float* ee = edge_emb + (size_t)mp * NEDGE * E;

    int nb[S], ed[S];
    if (r < 16384) {
        int node = __builtin_amdgcn_readfirstlane(gx[mp * RPM + r]);
        const int* an = adjn + ((size_t)mp * NNODES + node) * DEG;
        const int* ap = adje + ((size_t)mp * NNODES + node) * DEG;
#pragma unroll
        for (int j = 0; j < S; ++j) { nb[j] = an[j]; ed[j] = ap[j]; }
    } else {
        int b = __builtin_amdgcn_readfirstlane(r - 16384);
        const int* nbl = gx + mp * RPM + b * S;
        const int* edl = eid1 + mp * 16384 + b * S;
#pragma unroll
        for (int j = 0; j < S; ++j) { nb[j] = nbl[j]; ed[j] = edl[j]; }
    }

    // feature gathers: 16 independent full-wave loads (4 B/lane each)
    unsigned int fv[S];
#pragma unroll
    for (int j = 0; j < S; ++j)
        fv[j] = ((const unsigned int*)fb)[(size_t)nb[j] * 64 + t];

    // edge gathers: lanes 0-31 even neighbors, lanes 32-63 odd neighbors
    const int hi = t >> 5, t31 = t & 31;
    float ev[S / 2];
#pragma unroll
    for (int e = 0; e < S / 2; ++e) {
        int edd = hi ? ed[2 * e + 1] : ed[2 * e];
        ev[e] = ee[(size_t)edd * E + t31];
    }

    float s0 = 0.f, s1 = 0.f, se = 0.f;
#pragma unroll
    for (int j = 0; j < S; ++j) {
        s0 += bf2f((unsigned short)(fv[j] & 0xFFFF));
        s1 += bf2f((unsigned short)(fv[j] >> 16));
    }
#pragma unroll
    for (int e = 0; e < S / 2; ++e) se += ev[e];
    se += __shfl_xor(se, 32);          // combine even/odd halves

    const float inv = 1.0f / (float)S;
    unsigned short* row = nin + ((size_t)mp * RPM + r) * 160;
    ((unsigned int*)row)[t] =
        (unsigned int)f2bf(s0 * inv) | ((unsigned int)f2bf(s1 * inv) << 16);
    if (t < E) row[128 + t] = f2bf(se * inv);
}

// ---------- MFMA feat GEMM: out = relu(A @ [Wself;Wneigh]), K=288, N=128 ----------
// mode 0 (layer 0): A rows gathered from fb via gx; nin stride RPM; out bf16 fout
// mode 1 (layer 1): A rows direct from fout's f0 region; nin=agg1 stride B; out f32
__global__ __launch_bounds__(256) void gemm_feat_k(
    const unsigned short* __restrict__ fb, const int* __restrict__ gx,
    const unsigned short* __restrict__ fout_in,
    const unsigned short* __restrict__ nin,
    const unsigned short* __restrict__ WT0,
    unsigned short* __restrict__ outb, float* __restrict__ outf, int mode)
{
    const int mp = blockIdx.y;
    const int w = threadIdx.x >> 6;
    const int l = threadIdx.x & 63;
    const int q = l >> 4, lm = l & 15;
    const int m0 = blockIdx.x * 128 + w * 32;          // wave: 2 m-tiles (32 rows)
    const int ninStride = mode ? B : RPM;
    const unsigned short* wb = WT0 + ((size_t)mp * 2 + mode) * WSTRIDE;

    const unsigned short* ap[2];
    const unsigned short* np[2];
#pragma unroll
    for (int mt = 0; mt < 2; ++mt) {
        int row = m0 + mt * 16 + lm;
        if (mode == 0) {
            int node = gx[mp * RPM + row];
            ap[mt] = fb + (size_t)node * 128;
        } else {
            ap[mt] = fout_in + ((size_t)mp * RPM + 16384 + row) * 128;
        }
        np[mt] = nin + ((size_t)mp * ninStride + row) * 160;
    }

    f4 acc[2][8];
#pragma unroll
    for (int mt = 0; mt < 2; ++mt)
#pragma unroll
        for (int nt = 0; nt < 8; ++nt) acc[mt][nt] = (f4){0.f, 0.f, 0.f, 0.f};

#pragma unroll
    for (int kt = 0; kt < NKT; ++kt) {
        const int k0 = kt * 32 + q * 8;
        bh8 a[2];
#pragma unroll
        for (int mt = 0; mt < 2; ++mt) {
            const unsigned short* p = (k0 < 128) ? (ap[mt] + k0) : (np[mt] + (k0 - 128));
            a[mt] = *(const bh8*)p;
        }
        const unsigned short* wrow = wb + ((size_t)(kt * 4 + q) * 128 + lm) * 8;
#pragma unroll
        for (int nt = 0; nt < 8; ++nt) {
            bh8 bf = *(const bh8*)(wrow + nt * 16 * 8);
#pragma unroll
            for (int mt = 0; mt < 2; ++mt)
                acc[mt][nt] = __builtin_amdgcn_mfma_f32_16x16x32_bf16(a[mt], bf, acc[mt][nt], 0, 0, 0);
        }
    }

    if (mode == 0) {
#pragma unroll
        for (int mt = 0; mt < 2; ++mt)
#pragma unroll
            for (int nt = 0; nt < 8; ++nt)
#pragma unroll
                for (int rr = 0; rr < 4; ++rr) {
                    int row = m0 + mt * 16 + q * 4 + rr;   // C/D: col=lane&15, row=quad*4+reg
                    int col = nt * 16 + lm;
                    outb[((size_t)mp * RPM + row) * 128 + col] = f2bf(fmaxf(acc[mt][nt][rr], 0.f));
                }
    } else {
#pragma unroll
        for (int mt = 0; mt < 2; ++mt)
#pragma unroll
            for (int nt = 0; nt < 8; ++nt)
#pragma unroll
                for (int rr = 0; rr < 4; ++rr) {
                    int row = m0 + mt * 16 + q * 4 + rr;
                    int col = nt * 16 + lm;
                    outf[((size_t)mp * B + row) * 128 + col] = fmaxf(acc[mt][nt][rr], 0.f);
                }
    }
}

// ---------- MFMA edge GEMM: e0p = relu(concat(rep(f0,S), f1, E0) @ We), K=288, N=32 ----------
__global__ __launch_bounds__(256) void gemm_edge_k(
    const unsigned short* __restrict__ fout, const float* __restrict__ edge_emb,
    const int* __restrict__ eid1, const unsigned short* __restrict__ WTe,
    unsigned short* __restrict__ e0p)
{
    const int mp = blockIdx.y;
    const int w = threadIdx.x >> 6, l = threadIdx.x & 63;
    const int q = l >> 4, lm = l & 15;
    const int m0 = blockIdx.x * 128 + w * 32;          // wave: 2 m-tiles (32 rows)
    const unsigned short* we = WTe + (size_t)mp * WESTRIDE;
    const unsigned short* f1base = fout + (size_t)mp * RPM * 128;
    const unsigned short* f0base = fout + ((size_t)mp * RPM + 16384) * 128;
    const float* ee = edge_emb + (size_t)mp * NEDGE * E;

    const unsigned short* a1p[2];
    const unsigned short* a0p[2];
    int eidL[2];
#pragma unroll
    for (int mt = 0; mt < 2; ++mt) {
        int row = m0 + mt * 16 + lm;
        a1p[mt] = f1base + (size_t)row * 128;
        a0p[mt] = f0base + (size_t)(row >> 4) * 128;
        eidL[mt] = eid1[mp * 16384 + row];
    }

    f4 acc[2][2];
#pragma unroll
    for (int mt = 0; mt < 2; ++mt) { acc[mt][0] = (f4){0,0,0,0}; acc[mt][1] = (f4){0,0,0,0}; }

#pragma unroll
    for (int kt = 0; kt < NKT; ++kt) {
        const int k0 = kt * 32 + q * 8;
        bh8 a[2];
#pragma unroll
        for (int mt = 0; mt < 2; ++mt) {
            if (kt < 4) {
                a[mt] = *(const bh8*)(a0p[mt] + k0);
            } else if (kt < 8) {
                a[mt] = *(const bh8*)(a1p[mt] + (k0 - 128));
            } else {
                const float* ep = ee + (size_t)eidL[mt] * E + q * 8;
                float4 v0 = *(const float4*)ep;
                float4 v1 = *(const float4*)(ep + 4);
                bh8 tv;
                tv[0] = (short)f2bf(v0.x); tv[1] = (short)f2bf(v0.y);
                tv[2] = (short)f2bf(v0.z); tv[3] = (short)f2bf(v0.w);
                tv[4] = (short)f2bf(v1.x); tv[5] = (short)f2bf(v1.y);
                tv[6] = (short)f2bf(v1.z); tv[7] = (short)f2bf(v1.w);
                a[mt] = tv;
            }
        }
        const unsigned short* wrow = we + ((size_t)(kt * 4 + q) * 32 + lm) * 8;
        bh8 b0 = *(const bh8*)(wrow);
        bh8 b1 = *(const bh8*)(wrow + 16 * 8);
#pragma unroll
        for (int mt = 0; mt < 2; ++mt) {
            acc[mt][0] = __builtin_amdgcn_mfma_f32_16x16x32_bf16(a[mt], b0, acc[mt][0], 0, 0, 0);
            acc[mt][1] = __builtin_amdgcn_mfma_f32_16x16x32_bf16(a[mt], b1, acc[mt][1], 0, 0, 0);
        }
    }
#pragma unroll
    for (int mt = 0; mt < 2; ++mt)
#pragma unroll
        for (int nt = 0; nt < 2; ++nt)
#pragma unroll
            for (int rr = 0; rr < 4; ++rr) {
                int row = m0 + mt * 16 + q * 4 + rr;
                int col = nt * 16 + lm;
                e0p[((size_t)mp * 16384 + row) * 32 + col] = f2bf(fmaxf(acc[mt][nt][rr], 0.f));
            }
}

// ---------- layer-1 aggregation (sequential segments) -> agg1 [mp][B][160] bf16 ----------
__global__ __launch_bounds__(256) void aggseq_k(
    const unsigned short* __restrict__ fout, const unsigned short* __restrict__ e0p,
    unsigned short* __restrict__ agg1)
{
    int mp = blockIdx.y;
    int bRow = blockIdx.x * 4 + (threadIdx.x >> 6);   // < 1024
    int t = threadIdx.x & 63;
    const unsigned short* f1 = fout + ((size_t)mp * RPM + (size_t)bRow * 16) * 128;
    const unsigned short* e0 = e0p + ((size_t)mp * 16384 + (size_t)bRow * 16) * 32;
    float s0 = 0.f, s1 = 0.f, se = 0.f;
#pragma unroll
    for (int j = 0; j < S; ++j) {
        unsigned int u = ((const unsigned int*)(f1 + j * 128))[t];
        s0 += bf2f((unsigned short)(u & 0xFFFF));
        s1 += bf2f((unsigned short)(u >> 16));
        if (t < E) se += bf2f(e0[j * 32 + t]);
    }
    const float inv = 1.0f / (float)S;
    unsigned short* row = agg1 + ((size_t)mp * B + bRow) * 160;
    ((unsigned int*)row)[t] =
        (unsigned int)f2bf(s0 * inv) | ((unsigned int)f2bf(s1 * inv) << 16);
    if (t < E) row[128 + t] = f2bf(se * inv);
}

// ---------- metapath attention + normalize + fc ----------
__global__ __launch_bounds__(64) void finalize_k(
    const float* __restrict__ outs,     // [NMP][B][D] f32
    const float* __restrict__ attn, const float* __restrict__ fcw,
    const float* __restrict__ fcb, float* __restrict__ out)
{
    const int b = blockIdx.x;
    const int t = threadIdx.x;
    float v0[NMP], v1[NMP], sc[NMP];
    float at0 = attn[t], at1 = attn[64 + t];
#pragma unroll
    for (int mp = 0; mp < NMP; ++mp) {
        v0[mp] = outs[((size_t)mp * B + b) * D + t];
        v1[mp] = outs[((size_t)mp * B + b) * D + 64 + t];
        float p = v0[mp] * at0 + v1[mp] * at1;
#pragma unroll
        for (int off = 32; off; off >>= 1) p += __shfl_xor(p, off);
        sc[mp] = tanhf(p);
    }
    float mx = fmaxf(sc[0], fmaxf(sc[1], sc[2]));
    float e0 = expf(sc[0] - mx), e1 = expf(sc[1] - mx), e2 = expf(sc[2] - mx);
    float isum = 1.f / (e0 + e1 + e2);
    float b0 = e0 * isum, b1 = e1 * isum, b2 = e2 * isum;
    float emb0 = b0 * v0[0] + b1 * v0[1] + b2 * v0[2];
    float emb1 = b0 * v1[0] + b1 * v1[1] + b2 * v1[2];
    float nn = emb0 * emb0 + emb1 * emb1;
#pragma unroll
    for (int off = 32; off; off >>= 1) nn += __shfl_xor(nn, off);
    float innorm = 1.f / fmaxf(sqrtf(nn), 1e-12f);
    emb0 *= innorm; emb1 *= innorm;
    float pc[NC];
#pragma unroll
    for (int c = 0; c < NC; ++c) {
        float p = emb0 * fcw[t * NC + c] + emb1 * fcw[(64 + t) * NC + c];
#pragma unroll
        for (int off = 32; off; off >>= 1) p += __shfl_xor(p, off);
        pc[c] = p;
    }
    if (t == 0) {
#pragma unroll
        for (int c = 0; c < NC; ++c)
            out[(size_t)b * NC + c] = pc[c] + fcb[c];
    }
}

extern "C" void kernel_launch(void* const* d_in, const int* in_sizes, int n_in,
                              void* d_out, int out_size, void* d_ws, size_t ws_size,
                              hipStream_t stream) {
    const int* ids        = (const int*)d_in[0];
    const float* feats    = (const float*)d_in[1];
    const float* edge_emb = (const float*)d_in[2];
    const int* adjn       = (const int*)d_in[3];
    const int* adje       = (const int*)d_in[4];
    const float* Ws       = (const float*)d_in[5];
    const float* Wn       = (const float*)d_in[6];
    const float* We       = (const float*)d_in[7];
    const float* attn     = (const float*)d_in[8];
    const float* fcw      = (const float*)d_in[9];
    const float* fcb      = (const float*)d_in[10];
    float* out = (float*)d_out;

    // workspace layout (~49.5 MB; all regions fully written before read each call)
    char* p = (char*)d_ws;
    unsigned short* WT0 = (unsigned short*)p; p += (size_t)6 * WSTRIDE * 2;
    unsigned short* WTe = (unsigned short*)p; p += (size_t)3 * WESTRIDE * 2;
    unsigned short* fb  = (unsigned short*)p; p += (size_t)NNODES * 128 * 2;
    int* gx   = (int*)p;                      p += (size_t)3 * RPM * 4;
    int* eid1 = (int*)p;                      p += (size_t)3 * 16384 * 4;
    unsigned short* nin  = (unsigned short*)p; p += (size_t)3 * RPM * 160 * 2;
    unsigned short* fout = (unsigned short*)p; p += (size_t)3 * RPM * 128 * 2;
    unsigned short* e0p  = (unsigned short*)p; p += (size_t)3 * 16384 * 32 * 2;
    unsigned short* agg1 = (unsigned short*)p; p += (size_t)3 * B * 160 * 2;
    float* outs = (float*)p;                   p += (size_t)3 * B * 128 * 4;

    convert_k<<<7222, 256, 0, stream>>>(feats, Ws, Wn, We, fb, WT0, WTe);
    sample_k<<<dim3(68, 3), 256, 0, stream>>>(ids, adjn, adje, gx, eid1);
    aggnin_k<<<dim3(RPM / 4, 3), 256, 0, stream>>>(fb, edge_emb, adjn, adje, gx, eid1, nin);
    gemm_feat_k<<<dim3(136, 3), 256, 0, stream>>>(fb, gx, fout, nin, WT0, fout, nullptr, 0);
    gemm_edge_k<<<dim3(128, 3), 256, 0, stream>>>(fout, edge_emb, eid1, WTe, e0p);
    aggseq_k<<<dim3(256, 3), 256, 0, stream>>>(fout, e0p, agg1);
    gemm_feat_k<<<dim3(8, 3), 256, 0, stream>>>(fb, nullptr, fout, agg1, WT0, nullptr, outs, 1);
    finalize_k<<<B, 64, 0, stream>>>(outs, attn, fcw, fcb, out);
}

// Round 5
// 248.203 us; speedup vs baseline: 2.3774x; 1.0290x over previous
//
#include <hip/hip_runtime.h>

// Problem constants
#define NNODES  50000
#define D       128
#define E       32
#define NMP     3
#define DEG     32
#define NEDGE   200000
#define B       1024
#define NC      8
#define S       16

#define RPM      17408   // rows per mp in L0 row space (16384 level-1 + 1024 level-0)
#define NKT      9       // K tiles of 32 (K=288)
#define WSTRIDE  36864   // ushorts per (mp,lay) feat-weight block: 9*4*128*8
#define WESTRIDE 9216    // ushorts per mp edge-weight block: 9*4*32*8

typedef float f4 __attribute__((ext_vector_type(4)));
typedef short bh8 __attribute__((ext_vector_type(8)));   // 8 bf16 in 4 VGPRs

static __device__ __forceinline__ unsigned short f2bf(float f) {
    unsigned int u = __float_as_uint(f);
    u = u + 0x7FFFu + ((u >> 16) & 1u);   // RN-even
    return (unsigned short)(u >> 16);
}
static __device__ __forceinline__ float bf2f(unsigned short h) {
    return __uint_as_float(((unsigned int)h) << 16);
}

// ---------- one-shot conversions: feats->bf16 table, weights->swizzled bf16 frags ----------
// B-fragment order: dst[((kt*4+q)*N + n)*8 + j] = W[k = kt*32+q*8+j][n]
__global__ __launch_bounds__(256) void convert_k(
    const float* __restrict__ feats, const float* __restrict__ Ws,
    const float* __restrict__ Wn, const float* __restrict__ We,
    unsigned short* __restrict__ fb, unsigned short* __restrict__ WT0,
    unsigned short* __restrict__ WTe)
{
    int i = blockIdx.x * 256 + threadIdx.x;
    if (i < 1600000) {                          // feats: 50000*128/4 float4 tasks
        float4 v = ((const float4*)feats)[i];
        unsigned int p0 = (unsigned int)f2bf(v.x) | ((unsigned int)f2bf(v.y) << 16);
        unsigned int p1 = (unsigned int)f2bf(v.z) | ((unsigned int)f2bf(v.w) << 16);
        ((uint2*)fb)[i] = make_uint2(p0, p1);
    } else if (i < 1600000 + 6 * WSTRIDE) {     // feat weights: [mp][lay] K=288 (Ws||Wn), N=128
        int i2 = i - 1600000;
        int ml = i2 / WSTRIDE, e = i2 % WSTRIDE;
        int j = e & 7, t1 = e >> 3;
        int n = t1 & 127, t2 = t1 >> 7;
        int q = t2 & 3, kt = t2 >> 2;
        int k = kt * 32 + q * 8 + j;
        float v = (k < 128) ? Ws[((size_t)ml * 128 + k) * 128 + n]
                            : Wn[((size_t)ml * 160 + (k - 128)) * 128 + n];
        WT0[(size_t)ml * WSTRIDE + e] = f2bf(v);
    } else if (i < 1600000 + 6 * WSTRIDE + 3 * WESTRIDE) {  // edge weights: [mp][lay0] K=288,N=32
        int i3 = i - 1600000 - 6 * WSTRIDE;
        int mp = i3 / WESTRIDE, e = i3 % WESTRIDE;
        int j = e & 7, t1 = e >> 3;
        int n = t1 & 31, t2 = t1 >> 5;
        int q = t2 & 3, kt = t2 >> 2;
        int k = kt * 32 + q * 8 + j;
        float v = We[(((size_t)mp * 2) * 288 + k) * 32 + n];
        WTe[(size_t)mp * WESTRIDE + e] = f2bf(v);
    }
}

// ---------- level-1 sampling; gx row space: [0,16384)=cur1, [16384,17408)=ids ----------
__global__ __launch_bounds__(256) void sample_k(
    const int* __restrict__ ids, const int* __restrict__ adjn,
    const int* __restrict__ adje, int* __restrict__ gx, int* __restrict__ eid1)
{
    int mp = blockIdx.y;
    int i = blockIdx.x * 256 + threadIdx.x;
    const int* an = adjn + (size_t)mp * NNODES * DEG;
    const int* ae = adje + (size_t)mp * NNODES * DEG;
    if (i < 16384) {
        int node = ids[i >> 4];
        gx[mp * RPM + i]     = an[(size_t)node * DEG + (i & 15)];
        eid1[mp * 16384 + i] = ae[(size_t)node * DEG + (i & 15)];
    } else if (i < RPM) {
        gx[mp * RPM + i] = ids[i - 16384];
    }
}

// ---------- gather-mean -> nin [mp][RPM][160] bf16 ----------
// One wave per row. Branch only selects wave-uniform index-base pointers; all
// index values go through readfirstlane -> SGPRs (no per-lane arrays -> no LDS
// promotion). All 24 gathers issued straight-line before any use (full MLP).
__global__ __launch_bounds__(256) void aggnin_k(
    const unsigned short* __restrict__ fb, const float* __restrict__ edge_emb,
    const int* __restrict__ adjn, const int* __restrict__ adje,
    const int* __restrict__ gx, const int* __restrict__ eid1,
    unsigned short* __restrict__ nin)
{
    const int mp = blockIdx.y;
    const int r = blockIdx.x * 4 + (threadIdx.x >> 6);   // < 17408, wave-uniform
    const int t = threadIdx.x & 63;
    const float* ee = edge_emb + (size_t)mp * NEDGE * E;

    const int* ip;    // 16 neighbor node ids (wave-uniform base)
    const int* eix;   // 16 edge ids (wave-uniform base)
    if (r < 16384) {
        int node = __builtin_amdgcn_readfirstlane(gx[mp * RPM + r]);
        ip  = adjn + ((size_t)mp * NNODES + node) * DEG;
        eix = adje + ((size_t)mp * NNODES + node) * DEG;
    } else {
        ip  = gx + mp * RPM + (r - 16384) * S;
        eix = eid1 + mp * 16384 + (r - 16384) * S;
    }

    const int hi = t >> 5, t31 = t & 31;

    // feature gathers: 16 independent full-wave loads (256 B coalesced each)
    unsigned int fv[S];
#pragma unroll
    for (int j = 0; j < S; ++j) {
        int nb = __builtin_amdgcn_readfirstlane(ip[j]);
        fv[j] = ((const unsigned int*)fb)[(size_t)nb * 64 + t];
    }
    // edge gathers: lanes 0-31 even neighbor, lanes 32-63 odd neighbor
    float ev[S / 2];
#pragma unroll
    for (int e = 0; e < S / 2; ++e) {
        int e_ev = __builtin_amdgcn_readfirstlane(eix[2 * e]);
        int e_od = __builtin_amdgcn_readfirstlane(eix[2 * e + 1]);
        int edd = hi ? e_od : e_ev;
        ev[e] = ee[(size_t)edd * E + t31];
    }

    float s0 = 0.f, s1 = 0.f, se = 0.f;
#pragma unroll
    for (int j = 0; j < S; ++j) {
        s0 += bf2f((unsigned short)(fv[j] & 0xFFFF));
        s1 += bf2f((unsigned short)(fv[j] >> 16));
    }
#pragma unroll
    for (int e = 0; e < S / 2; ++e) se += ev[e];
    se += __shfl_xor(se, 32);          // combine even/odd halves

    const float inv = 1.0f / (float)S;
    unsigned short* row = nin + ((size_t)mp * RPM + r) * 160;
    ((unsigned int*)row)[t] =
        (unsigned int)f2bf(s0 * inv) | ((unsigned int)f2bf(s1 * inv) << 16);
    if (t < E) row[128 + t] = f2bf(se * inv);
}

// ---------- MFMA feat GEMM: out = relu(A @ [Wself;Wneigh]), K=288, N=128 ----------
// mode 0 (layer 0): A rows gathered from fb via gx; nin stride RPM; out bf16 fout
// mode 1 (layer 1): A rows direct from fout's f0 region; nin=agg1 stride B; out f32
__global__ __launch_bounds__(256) void gemm_feat_k(
    const unsigned short* __restrict__ fb, const int* __restrict__ gx,
    const unsigned short* __restrict__ fout_in,
    const unsigned short* __restrict__ nin,
    const unsigned short* __restrict__ WT0,
    unsigned short* __restrict__ outb, float* __restrict__ outf, int mode)
{
    const int mp = blockIdx.y;
    const int w = threadIdx.x >> 6;
    const int l = threadIdx.x & 63;
    const int q = l >> 4, lm = l & 15;
    const int m0 = blockIdx.x * 128 + w * 32;          // wave: 2 m-tiles (32 rows)
    const int ninStride = mode ? B : RPM;
    const unsigned short* wb = WT0 + ((size_t)mp * 2 + mode) * WSTRIDE;

    const unsigned short* ap[2];
    const unsigned short* np[2];
#pragma unroll
    for (int mt = 0; mt < 2; ++mt) {
        int row = m0 + mt * 16 + lm;
        if (mode == 0) {
            int node = gx[mp * RPM + row];
            ap[mt] = fb + (size_t)node * 128;
        } else {
            ap[mt] = fout_in + ((size_t)mp * RPM + 16384 + row) * 128;
        }
        np[mt] = nin + ((size_t)mp * ninStride + row) * 160;
    }

    f4 acc[2][8];
#pragma unroll
    for (int mt = 0; mt < 2; ++mt)
#pragma unroll
        for (int nt = 0; nt < 8; ++nt) acc[mt][nt] = (f4){0.f, 0.f, 0.f, 0.f};

#pragma unroll
    for (int kt = 0; kt < NKT; ++kt) {
        const int k0 = kt * 32 + q * 8;
        bh8 a[2];
#pragma unroll
        for (int mt = 0; mt < 2; ++mt) {
            const unsigned short* p = (k0 < 128) ? (ap[mt] + k0) : (np[mt] + (k0 - 128));
            a[mt] = *(const bh8*)p;
        }
        const unsigned short* wrow = wb + ((size_t)(kt * 4 + q) * 128 + lm) * 8;
#pragma unroll
        for (int nt = 0; nt < 8; ++nt) {
            bh8 bf = *(const bh8*)(wrow + nt * 16 * 8);
#pragma unroll
            for (int mt = 0; mt < 2; ++mt)
                acc[mt][nt] = __builtin_amdgcn_mfma_f32_16x16x32_bf16(a[mt], bf, acc[mt][nt], 0, 0, 0);
        }
    }

    if (mode == 0) {
#pragma unroll
        for (int mt = 0; mt < 2; ++mt)
#pragma unroll
            for (int nt = 0; nt < 8; ++nt)
#pragma unroll
                for (int rr = 0; rr < 4; ++rr) {
                    int row = m0 + mt * 16 + q * 4 + rr;   // C/D: col=lane&15, row=quad*4+reg
                    int col = nt * 16 + lm;
                    outb[((size_t)mp * RPM + row) * 128 + col] = f2bf(fmaxf(acc[mt][nt][rr], 0.f));
                }
    } else {
#pragma unroll
        for (int mt = 0; mt < 2; ++mt)
#pragma unroll
            for (int nt = 0; nt < 8; ++nt)
#pragma unroll
                for (int rr = 0; rr < 4; ++rr) {
                    int row = m0 + mt * 16 + q * 4 + rr;
                    int col = nt * 16 + lm;
                    outf[((size_t)mp * B + row) * 128 + col] = fmaxf(acc[mt][nt][rr], 0.f);
                }
    }
}

// ---------- MFMA edge GEMM: e0p = relu(concat(rep(f0,S), f1, E0) @ We), K=288, N=32 ----------
__global__ __launch_bounds__(256) void gemm_edge_k(
    const unsigned short* __restrict__ fout, const float* __restrict__ edge_emb,
    const int* __restrict__ eid1, const unsigned short* __restrict__ WTe,
    unsigned short* __restrict__ e0p)
{
    const int mp = blockIdx.y;
    const int w = threadIdx.x >> 6, l = threadIdx.x & 63;
    const int q = l >> 4, lm = l & 15;
    const int m0 = blockIdx.x * 128 + w * 32;          // wave: 2 m-tiles (32 rows)
    const unsigned short* we = WTe + (size_t)mp * WESTRIDE;
    const unsigned short* f1base = fout + (size_t)mp * RPM * 128;
    const unsigned short* f0base = fout + ((size_t)mp * RPM + 16384) * 128;
    const float* ee = edge_emb + (size_t)mp * NEDGE * E;

    const unsigned short* a1p[2];
    const unsigned short* a0p[2];
    int eidL[2];
#pragma unroll
    for (int mt = 0; mt < 2; ++mt) {
        int row = m0 + mt * 16 + lm;
        a1p[mt] = f1base + (size_t)row * 128;
        a0p[mt] = f0base + (size_t)(row >> 4) * 128;
        eidL[mt] = eid1[mp * 16384 + row];
    }

    f4 acc[2][2];
#pragma unroll
    for (int mt = 0; mt < 2; ++mt) { acc[mt][0] = (f4){0,0,0,0}; acc[mt][1] = (f4){0,0,0,0}; }

#pragma unroll
    for (int kt = 0; kt < NKT; ++kt) {
        const int k0 = kt * 32 + q * 8;
        bh8 a[2];
#pragma unroll
        for (int mt = 0; mt < 2; ++mt) {
            if (kt < 4) {
                a[mt] = *(const bh8*)(a0p[mt] + k0);
            } else if (kt < 8) {
                a[mt] = *(const bh8*)(a1p[mt] + (k0 - 128));
            } else {
                const float* ep = ee + (size_t)eidL[mt] * E + q * 8;
                float4 v0 = *(const float4*)ep;
                float4 v1 = *(const float4*)(ep + 4);
                bh8 tv;
                tv[0] = (short)f2bf(v0.x); tv[1] = (short)f2bf(v0.y);
                tv[2] = (short)f2bf(v0.z); tv[3] = (short)f2bf(v0.w);
                tv[4] = (short)f2bf(v1.x); tv[5] = (short)f2bf(v1.y);
                tv[6] = (short)f2bf(v1.z); tv[7] = (short)f2bf(v1.w);
                a[mt] = tv;
            }
        }
        const unsigned short* wrow = we + ((size_t)(kt * 4 + q) * 32 + lm) * 8;
        bh8 b0 = *(const bh8*)(wrow);
        bh8 b1 = *(const bh8*)(wrow + 16 * 8);
#pragma unroll
        for (int mt = 0; mt < 2; ++mt) {
            acc[mt][0] = __builtin_amdgcn_mfma_f32_16x16x32_bf16(a[mt], b0, acc[mt][0], 0, 0, 0);
            acc[mt][1] = __builtin_amdgcn_mfma_f32_16x16x32_bf16(a[mt], b1, acc[mt][1], 0, 0, 0);
        }
    }
#pragma unroll
    for (int mt = 0; mt < 2; ++mt)
#pragma unroll
        for (int nt = 0; nt < 2; ++nt)
#pragma unroll
            for (int rr = 0; rr < 4; ++rr) {
                int row = m0 + mt * 16 + q * 4 + rr;
                int col = nt * 16 + lm;
                e0p[((size_t)mp * 16384 + row) * 32 + col] = f2bf(fmaxf(acc[mt][nt][rr], 0.f));
            }
}

// ---------- layer-1 aggregation (sequential segments) -> agg1 [mp][B][160] bf16 ----------
__global__ __launch_bounds__(256) void aggseq_k(
    const unsigned short* __restrict__ fout, const unsigned short* __restrict__ e0p,
    unsigned short* __restrict__ agg1)
{
    int mp = blockIdx.y;
    int bRow = blockIdx.x * 4 + (threadIdx.x >> 6);   // < 1024
    int t = threadIdx.x & 63;
    const unsigned short* f1 = fout + ((size_t)mp * RPM + (size_t)bRow * 16) * 128;
    const unsigned short* e0 = e0p + ((size_t)mp * 16384 + (size_t)bRow * 16) * 32;
    float s0 = 0.f, s1 = 0.f, se = 0.f;
#pragma unroll
    for (int j = 0; j < S; ++j) {
        unsigned int u = ((const unsigned int*)(f1 + j * 128))[t];
        s0 += bf2f((unsigned short)(u & 0xFFFF));
        s1 += bf2f((unsigned short)(u >> 16));
        if (t < E) se += bf2f(e0[j * 32 + t]);
    }
    const float inv = 1.0f / (float)S;
    unsigned short* row = agg1 + ((size_t)mp * B + bRow) * 160;
    ((unsigned int*)row)[t] =
        (unsigned int)f2bf(s0 * inv) | ((unsigned int)f2bf(s1 * inv) << 16);
    if (t < E) row[128 + t] = f2bf(se * inv);
}

// ---------- metapath attention + normalize + fc ----------
__global__ __launch_bounds__(64) void finalize_k(
    const float* __restrict__ outs,     // [NMP][B][D] f32
    const float* __restrict__ attn, const float* __restrict__ fcw,
    const float* __restrict__ fcb, float* __restrict__ out)
{
    const int b = blockIdx.x;
    const int t = threadIdx.x;
    float v0[NMP], v1[NMP], sc[NMP];
    float at0 = attn[t], at1 = attn[64 + t];
#pragma unroll
    for (int mp = 0; mp < NMP; ++mp) {
        v0[mp] = outs[((size_t)mp * B + b) * D + t];
        v1[mp] = outs[((size_t)mp * B + b) * D + 64 + t];
        float p = v0[mp] * at0 + v1[mp] * at1;
#pragma unroll
        for (int off = 32; off; off >>= 1) p += __shfl_xor(p, off);
        sc[mp] = tanhf(p);
    }
    float mx = fmaxf(sc[0], fmaxf(sc[1], sc[2]));
    float e0 = expf(sc[0] - mx), e1 = expf(sc[1] - mx), e2 = expf(sc[2] - mx);
    float isum = 1.f / (e0 + e1 + e2);
    float b0 = e0 * isum, b1 = e1 * isum, b2 = e2 * isum;
    float emb0 = b0 * v0[0] + b1 * v0[1] + b2 * v0[2];
    float emb1 = b0 * v1[0] + b1 * v1[1] + b2 * v1[2];
    float nn = emb0 * emb0 + emb1 * emb1;
#pragma unroll
    for (int off = 32; off; off >>= 1) nn += __shfl_xor(nn, off);
    float innorm = 1.f / fmaxf(sqrtf(nn), 1e-12f);
    emb0 *= innorm; emb1 *= innorm;
    float pc[NC];
#pragma unroll
    for (int c = 0; c < NC; ++c) {
        float p = emb0 * fcw[t * NC + c] + emb1 * fcw[(64 + t) * NC + c];
#pragma unroll
        for (int off = 32; off; off >>= 1) p += __shfl_xor(p, off);
        pc[c] = p;
    }
    if (t == 0) {
#pragma unroll
        for (int c = 0; c < NC; ++c)
            out[(size_t)b * NC + c] = pc[c] + fcb[c];
    }
}

extern "C" void kernel_launch(void* const* d_in, const int* in_sizes, int n_in,
                              void* d_out, int out_size, void* d_ws, size_t ws_size,
                              hipStream_t stream) {
    const int* ids        = (const int*)d_in[0];
    const float* feats    = (const float*)d_in[1];
    const float* edge_emb = (const float*)d_in[2];
    const int* adjn       = (const int*)d_in[3];
    const int* adje       = (const int*)d_in[4];
    const float* Ws       = (const float*)d_in[5];
    const float* Wn       = (const float*)d_in[6];
    const float* We       = (const float*)d_in[7];
    const float* attn     = (const float*)d_in[8];
    const float* fcw      = (const float*)d_in[9];
    const float* fcb      = (const float*)d_in[10];
    float* out = (float*)d_out;

    // workspace layout (~49.5 MB; all regions fully written before read each call)
    char* p = (char*)d_ws;
    unsigned short* WT0 = (unsigned short*)p; p += (size_t)6 * WSTRIDE * 2;
    unsigned short* WTe = (unsigned short*)p; p += (size_t)3 * WESTRIDE * 2;
    unsigned short* fb  = (unsigned short*)p; p += (size_t)NNODES * 128 * 2;
    int* gx   = (int*)p;                      p += (size_t)3 * RPM * 4;
    int* eid1 = (int*)p;                      p += (size_t)3 * 16384 * 4;
    unsigned short* nin  = (unsigned short*)p; p += (size_t)3 * RPM * 160 * 2;
    unsigned short* fout = (unsigned short*)p; p += (size_t)3 * RPM * 128 * 2;
    unsigned short* e0p  = (unsigned short*)p; p += (size_t)3 * 16384 * 32 * 2;
    unsigned short* agg1 = (unsigned short*)p; p += (size_t)3 * B * 160 * 2;
    float* outs = (float*)p;                   p += (size_t)3 * B * 128 * 4;

    convert_k<<<7222, 256, 0, stream>>>(feats, Ws, Wn, We, fb, WT0, WTe);
    sample_k<<<dim3(68, 3), 256, 0, stream>>>(ids, adjn, adje, gx, eid1);
    aggnin_k<<<dim3(RPM / 4, 3), 256, 0, stream>>>(fb, edge_emb, adjn, adje, gx, eid1, nin);
    gemm_feat_k<<<dim3(136, 3), 256, 0, stream>>>(fb, gx, fout, nin, WT0, fout, nullptr, 0);
    gemm_edge_k<<<dim3(128, 3), 256, 0, stream>>>(fout, edge_emb, eid1, WTe, e0p);
    aggseq_k<<<dim3(256, 3), 256, 0, stream>>>(fout, e0p, agg1);
    gemm_feat_k<<<dim3(8, 3), 256, 0, stream>>>(fb, nullptr, fout, agg1, WT0, nullptr, outs, 1);
    finalize_k<<<B, 64, 0, stream>>>(outs, attn, fcw, fcb, out);
}